// Round 6
// baseline (6970.349 us; speedup 1.0000x reference)
//
#include <hip/hip_runtime.h>
#include <math.h>

// ---------------- problem constants ----------------
#define BATCH 4096
#define TLEN  64
#define CIN   32
#define HID   128
#define BRD   64
#define FCD   128
#define NTR   4
#define LIPC  1.9679896712654303f   // 15^0.25

// output offsets (floats)
#define BAL_OFF 0
#define TPR_OFF 16777216u           // 4096*64*64
#define OUT_OFF 17825792u           // + 4096*64*4
#define HO_OFF  18087936u           // + 4096*64*1
#define CO_OFF  18612224u           // + 4096*128

// workspace layout (floats)
#define SC_OFF   0
#define BZ_OFF   16
#define WT_OFF   1024                         // [160][512]
#define WBRT_OFF (WT_OFF + 160*512)           // [128][64]
#define WT1T_OFF (WBRT_OFF + 128*64)          // [64][128]
#define WO1T_OFF (WT1T_OFF + 64*128)          // [68][128]
#define WO2_OFF  (WO1T_OFF + 68*128)          // [128]

__device__ __forceinline__ float sigm_(float x) {
    return __fdividef(1.f, 1.f + __expf(-x));
}
__device__ __forceinline__ float tanh_(float x) {
    x = fminf(fmaxf(x, -30.f), 30.f);
    float e = __expf(2.f * x);
    return (e - 1.f) * __fdividef(1.f, e + 1.f);
}
__device__ __forceinline__ float elu_(float x) {
    return x > 0.f ? x : (__expf(x) - 1.f);
}

// ---------------- kernel 1: Frobenius-norm scales ----------------
__global__ void norms_k(const float* __restrict__ Wih, const float* __restrict__ Whh,
                        const float* __restrict__ Wbr, const float* __restrict__ Wo1,
                        const float* __restrict__ Wo2, float* __restrict__ ws) {
    __shared__ float red[4];
    const float* ptr; int n;
    switch (blockIdx.x) {
        case 0: ptr = Wih; n = 512 * 32;  break;
        case 1: ptr = Whh; n = 512 * 128; break;
        case 2: ptr = Wbr; n = 64 * 128;  break;
        case 3: ptr = Wo1; n = 128 * 68;  break;
        default: ptr = Wo2; n = 128;      break;
    }
    float s = 0.f;
    for (int i = threadIdx.x; i < n; i += 256) { float v = ptr[i]; s += v * v; }
    s += __shfl_down(s, 32); s += __shfl_down(s, 16); s += __shfl_down(s, 8);
    s += __shfl_down(s, 4);  s += __shfl_down(s, 2);  s += __shfl_down(s, 1);
    if ((threadIdx.x & 63) == 0) red[threadIdx.x >> 6] = s;
    __syncthreads();
    if (threadIdx.x == 0) {
        float tot = red[0] + red[1] + red[2] + red[3];
        ws[SC_OFF + blockIdx.x] = fminf(1.f, LIPC / (sqrtf(tot) + 1e-12f));
    }
}

// ---------------- kernel 2: scaled transposed weights into ws ----------------
__global__ void prep_k(const float* __restrict__ Wih, const float* __restrict__ Whh,
                       const float* __restrict__ bih, const float* __restrict__ bhh,
                       const float* __restrict__ Wbr, const float* __restrict__ Wt1,
                       const float* __restrict__ Wo1, const float* __restrict__ Wo2,
                       float* __restrict__ ws) {
    const float s_ih = ws[SC_OFF + 0], s_hh = ws[SC_OFF + 1], s_br = ws[SC_OFF + 2];
    const float s_o1 = ws[SC_OFF + 3], s_o2 = ws[SC_OFF + 4];
    const int stride = gridDim.x * blockDim.x;
    const int t0 = blockIdx.x * blockDim.x + threadIdx.x;
    for (int i = t0; i < 160 * 512; i += stride) {
        int k = i >> 9, j = i & 511;
        ws[WT_OFF + i] = (k < 32) ? Wih[j * 32 + k] * s_ih : Whh[j * 128 + (k - 32)] * s_hh;
    }
    for (int i = t0; i < 128 * 64; i += stride) { int k = i >> 6, j = i & 63;  ws[WBRT_OFF + i] = Wbr[j * 128 + k] * s_br; }
    for (int i = t0; i < 64 * 128; i += stride) { int k = i >> 7, j = i & 127; ws[WT1T_OFF + i] = Wt1[j * 64 + k]; }
    for (int i = t0; i < 68 * 128; i += stride) { int k = i >> 7, j = i & 127; ws[WO1T_OFF + i] = Wo1[j * 68 + k] * s_o1; }
    for (int i = t0; i < 128; i += stride)      ws[WO2_OFF + i] = Wo2[i] * s_o2;
    for (int i = t0; i < 512; i += stride)      ws[BZ_OFF + i] = bih[i] + bhh[i];
}

// ---------------- kernel 3: the recurrent network ----------------
#define FMA4(r, base, f, V)                                  \
    acc[r][base + 0] = fmaf(f, V.x, acc[r][base + 0]);       \
    acc[r][base + 1] = fmaf(f, V.y, acc[r][base + 1]);       \
    acc[r][base + 2] = fmaf(f, V.z, acc[r][base + 2]);       \
    acc[r][base + 3] = fmaf(f, V.w, acc[r][base + 3]);

__global__ __launch_bounds__(256) void crn_main(
    const float* __restrict__ cov, const float* __restrict__ treat,
    const float* __restrict__ h0, const float* __restrict__ c0,
    const float* __restrict__ b_br, const float* __restrict__ b_t1,
    const float* __restrict__ Wt2, const float* __restrict__ b_t2,
    const float* __restrict__ b_o1, const float* __restrict__ b_o2,
    const float* __restrict__ ws, float* __restrict__ out) {

    __shared__ float xh[16][164];     // cols 0..31 = x_t, 32..159 = h
    __shared__ float br_s[16][72];    // 0..63 = br, 64..67 = treat_t
    __shared__ float ht_s[16][132];   // t-head hidden
    __shared__ float ho_s[16][132];   // o-head hidden
    __shared__ float tl_s[16][4];
    __shared__ float oc_s[16];
    __shared__ float bz_s[512];
    __shared__ float bbr_s[64], bt1_s[128], bo1_s[128], bt2_s[4];
    __shared__ float bo2_s;

    const int tid = threadIdx.x;
    const int tx = tid & 31;
    const int ty = tid >> 5;            // 0..7
    const int row0 = 2 * ty, row1 = 2 * ty + 1;
    const int r0 = blockIdx.x * 16;     // first batch row of this block

    // ---- stage biases / initial state ----
    for (int i = tid; i < 512; i += 256) bz_s[i] = ws[BZ_OFF + i];
    if (tid < 64) bbr_s[tid] = b_br[tid];
    if (tid < 128) bt1_s[tid] = b_t1[tid];
    else if (tid < 256) bo1_s[tid - 128] = b_o1[tid - 128];
    if (tid < 4) bt2_s[tid] = b_t2[tid];
    if (tid == 4) bo2_s = b_o2[0];
    for (int i = tid; i < 16 * 128; i += 256) {
        int b = i >> 7, u = i & 127;
        xh[b][32 + u] = h0[(size_t)(r0 + b) * 128 + u];
    }
    float c_reg[2][4];
    {
        float4 ca = *(const float4*)&c0[(size_t)(r0 + row0) * 128 + 4 * tx];
        float4 cb = *(const float4*)&c0[(size_t)(r0 + row1) * 128 + 4 * tx];
        c_reg[0][0] = ca.x; c_reg[0][1] = ca.y; c_reg[0][2] = ca.z; c_reg[0][3] = ca.w;
        c_reg[1][0] = cb.x; c_reg[1][1] = cb.y; c_reg[1][2] = cb.z; c_reg[1][3] = cb.w;
    }
    __syncthreads();

    const float4* WT4  = (const float4*)(ws + WT_OFF);
    const float2* WBR2 = (const float2*)(ws + WBRT_OFF);
    const float4* WT14 = (const float4*)(ws + WT1T_OFF);
    const float4* WO14 = (const float4*)(ws + WO1T_OFF);
    const float*  WO2v = ws + WO2_OFF;

    for (int t = 0; t < TLEN; ++t) {
        // ---- phase A: load x_t (with outcome feedback) and treat_t ----
        for (int i = tid; i < 512; i += 256) {
            int b = i >> 5, k = i & 31;
            float v = cov[(size_t)(r0 + b) * (TLEN * CIN) + t * CIN + k];
            if (t > 0 && k == 27) v = oc_s[b];
            xh[b][k] = v;
        }
        if (tid < 64) {
            int b = tid >> 2, n = tid & 3;
            br_s[b][64 + n] = treat[(size_t)(r0 + b) * (TLEN * NTR) + t * NTR + n];
        }
        __syncthreads();

        // ---- phase B: z = [x|h] @ WT + bz   (thread: 2 rows x 16 gate-cols) ----
        float acc[2][16];
        #pragma unroll
        for (int g = 0; g < 4; ++g)
            #pragma unroll
            for (int i2 = 0; i2 < 4; ++i2) {
                float bv = bz_s[128 * g + 4 * tx + i2];
                acc[0][g * 4 + i2] = bv; acc[1][g * 4 + i2] = bv;
            }
        {
            const float4* xa = (const float4*)&xh[row0][0];
            const float4* xb = (const float4*)&xh[row1][0];
            for (int k4 = 0; k4 < 40; ++k4) {
                float4 ha = xa[k4], hb = xb[k4];
                #pragma unroll
                for (int kk = 0; kk < 4; ++kk) {
                    const float4* wp = WT4 + (size_t)(4 * k4 + kk) * 128 + tx;
                    float4 w0 = wp[0], w1 = wp[32], w2 = wp[64], w3 = wp[96];
                    float fa = (kk == 0) ? ha.x : (kk == 1) ? ha.y : (kk == 2) ? ha.z : ha.w;
                    float fb = (kk == 0) ? hb.x : (kk == 1) ? hb.y : (kk == 2) ? hb.z : hb.w;
                    FMA4(0, 0, fa, w0) FMA4(0, 4, fa, w1) FMA4(0, 8, fa, w2) FMA4(0, 12, fa, w3)
                    FMA4(1, 0, fb, w0) FMA4(1, 4, fb, w1) FMA4(1, 8, fb, w2) FMA4(1, 12, fb, w3)
                }
            }
        }
        __syncthreads();   // all reads of old h complete

        // ---- phase C: gates -> h2, c2 (fully thread-local) ----
        #pragma unroll
        for (int r = 0; r < 2; ++r) {
            int row = (r == 0) ? row0 : row1;
            float hv[4];
            #pragma unroll
            for (int u4 = 0; u4 < 4; ++u4) {
                float iv = sigm_(acc[r][u4]);
                float fv = sigm_(acc[r][4 + u4]);
                float gv = tanh_(acc[r][8 + u4]);
                float ov = sigm_(acc[r][12 + u4]);
                float c2 = fv * c_reg[r][u4] + iv * gv;
                c_reg[r][u4] = c2;
                hv[u4] = ov * tanh_(c2);
            }
            float4 h4 = make_float4(hv[0], hv[1], hv[2], hv[3]);
            *(float4*)&xh[row][32 + 4 * tx] = h4;
            if (t == TLEN - 1) {
                *(float4*)&out[HO_OFF + (size_t)(r0 + row) * 128 + 4 * tx] = h4;
                *(float4*)&out[CO_OFF + (size_t)(r0 + row) * 128 + 4 * tx] =
                    make_float4(c_reg[r][0], c_reg[r][1], c_reg[r][2], c_reg[r][3]);
            }
        }
        __syncthreads();   // h2 visible

        // ---- phase D: br = elu(h @ WbrT + b_br)  [16x64] ----
        {
            float a00 = bbr_s[2 * tx], a01 = bbr_s[2 * tx + 1];
            float a10 = a00, a11 = a01;
            const float4* xa = (const float4*)&xh[row0][32];
            const float4* xb = (const float4*)&xh[row1][32];
            for (int k4 = 0; k4 < 32; ++k4) {
                float4 ha = xa[k4], hb = xb[k4];
                #pragma unroll
                for (int kk = 0; kk < 4; ++kk) {
                    float2 wv = WBR2[(size_t)(4 * k4 + kk) * 32 + tx];
                    float fa = (kk == 0) ? ha.x : (kk == 1) ? ha.y : (kk == 2) ? ha.z : ha.w;
                    float fb = (kk == 0) ? hb.x : (kk == 1) ? hb.y : (kk == 2) ? hb.z : hb.w;
                    a00 = fmaf(fa, wv.x, a00); a01 = fmaf(fa, wv.y, a01);
                    a10 = fmaf(fb, wv.x, a10); a11 = fmaf(fb, wv.y, a11);
                }
            }
            a00 = elu_(a00); a01 = elu_(a01); a10 = elu_(a10); a11 = elu_(a11);
            br_s[row0][2 * tx] = a00; br_s[row0][2 * tx + 1] = a01;
            br_s[row1][2 * tx] = a10; br_s[row1][2 * tx + 1] = a11;
            *(float2*)&out[BAL_OFF + (size_t)(r0 + row0) * (TLEN * BRD) + t * BRD + 2 * tx] = make_float2(a00, a01);
            *(float2*)&out[BAL_OFF + (size_t)(r0 + row1) * (TLEN * BRD) + t * BRD + 2 * tx] = make_float2(a10, a11);
        }
        __syncthreads();

        // ---- phase E: ht = elu(br @ Wt1T + b_t1), ho = elu([br|treat] @ Wo1T + b_o1) ----
        {
            float at[2][4], ao[2][4];
            #pragma unroll
            for (int i2 = 0; i2 < 4; ++i2) {
                float bt = bt1_s[4 * tx + i2], bo = bo1_s[4 * tx + i2];
                at[0][i2] = bt; at[1][i2] = bt; ao[0][i2] = bo; ao[1][i2] = bo;
            }
            const float4* ba = (const float4*)&br_s[row0][0];
            const float4* bb = (const float4*)&br_s[row1][0];
            for (int k4 = 0; k4 < 17; ++k4) {        // k = 0..67 (t1 stops at 63)
                float4 ka = ba[k4], kb = bb[k4];
                #pragma unroll
                for (int kk = 0; kk < 4; ++kk) {
                    int k = 4 * k4 + kk;
                    float fa = (kk == 0) ? ka.x : (kk == 1) ? ka.y : (kk == 2) ? ka.z : ka.w;
                    float fb = (kk == 0) ? kb.x : (kk == 1) ? kb.y : (kk == 2) ? kb.z : kb.w;
                    float4 wo = WO14[(size_t)k * 32 + tx];
                    ao[0][0] = fmaf(fa, wo.x, ao[0][0]); ao[0][1] = fmaf(fa, wo.y, ao[0][1]);
                    ao[0][2] = fmaf(fa, wo.z, ao[0][2]); ao[0][3] = fmaf(fa, wo.w, ao[0][3]);
                    ao[1][0] = fmaf(fb, wo.x, ao[1][0]); ao[1][1] = fmaf(fb, wo.y, ao[1][1]);
                    ao[1][2] = fmaf(fb, wo.z, ao[1][2]); ao[1][3] = fmaf(fb, wo.w, ao[1][3]);
                    if (k < 64) {
                        float4 wt = WT14[(size_t)k * 32 + tx];
                        at[0][0] = fmaf(fa, wt.x, at[0][0]); at[0][1] = fmaf(fa, wt.y, at[0][1]);
                        at[0][2] = fmaf(fa, wt.z, at[0][2]); at[0][3] = fmaf(fa, wt.w, at[0][3]);
                        at[1][0] = fmaf(fb, wt.x, at[1][0]); at[1][1] = fmaf(fb, wt.y, at[1][1]);
                        at[1][2] = fmaf(fb, wt.z, at[1][2]); at[1][3] = fmaf(fb, wt.w, at[1][3]);
                    }
                }
            }
            #pragma unroll
            for (int r = 0; r < 2; ++r) {
                int row = (r == 0) ? row0 : row1;
                *(float4*)&ht_s[row][4 * tx] = make_float4(elu_(at[r][0]), elu_(at[r][1]), elu_(at[r][2]), elu_(at[r][3]));
                *(float4*)&ho_s[row][4 * tx] = make_float4(elu_(ao[r][0]), elu_(ao[r][1]), elu_(ao[r][2]), elu_(ao[r][3]));
            }
        }
        __syncthreads();

        // ---- phase F: tl = ht @ Wt2T + b_t2 ; oc = ho @ Wo2 + b_o2 ----
        {
            // t2: 64 outputs, 4-lane k-split (strided so LDS banks spread)
            int out_id = tid >> 2;             // 0..63
            int b = out_id >> 2, n = out_id & 3, op = tid & 3;
            float s = 0.f;
            #pragma unroll
            for (int k = 0; k < 32; ++k) {
                int kk = 4 * k + op;
                s = fmaf(ht_s[b][kk], Wt2[n * 128 + kk], s);
            }
            s += __shfl_xor(s, 1);
            s += __shfl_xor(s, 2);
            if (op == 0) tl_s[b][n] = s + bt2_s[n];

            // o2: 16 outputs, 16-lane k-split
            int b2 = tid >> 4, p2 = tid & 15;
            float s2 = 0.f;
            #pragma unroll
            for (int k = 0; k < 8; ++k) {
                int kk = p2 + 16 * k;
                s2 = fmaf(ho_s[b2][kk], WO2v[kk], s2);
            }
            s2 += __shfl_xor(s2, 1); s2 += __shfl_xor(s2, 2);
            s2 += __shfl_xor(s2, 4); s2 += __shfl_xor(s2, 8);
            if (p2 == 0) {
                float oc = s2 + bo2_s;
                oc_s[b2] = oc;
                out[OUT_OFF + (size_t)(r0 + b2) * TLEN + t] = oc;
            }
        }
        __syncthreads();

        // ---- softmax over treatment logits ----
        if (tid < 16) {
            float l0 = tl_s[tid][0], l1 = tl_s[tid][1], l2 = tl_s[tid][2], l3 = tl_s[tid][3];
            float m = fmaxf(fmaxf(l0, l1), fmaxf(l2, l3));
            float e0 = __expf(l0 - m), e1 = __expf(l1 - m), e2 = __expf(l2 - m), e3 = __expf(l3 - m);
            float inv = __fdividef(1.f, e0 + e1 + e2 + e3);
            *(float4*)&out[TPR_OFF + (size_t)(r0 + tid) * (TLEN * NTR) + t * NTR] =
                make_float4(e0 * inv, e1 * inv, e2 * inv, e3 * inv);
        }
        // next phase A only reads oc_s (barrier above covers it) and writes x-region of xh
    }
}

extern "C" void kernel_launch(void* const* d_in, const int* in_sizes, int n_in,
                              void* d_out, int out_size, void* d_ws, size_t ws_size,
                              hipStream_t stream) {
    const float* cov  = (const float*)d_in[0];
    const float* trt  = (const float*)d_in[1];
    const float* h0   = (const float*)d_in[2];
    const float* c0   = (const float*)d_in[3];
    const float* Wih  = (const float*)d_in[5];
    const float* Whh  = (const float*)d_in[6];
    const float* bih  = (const float*)d_in[7];
    const float* bhh  = (const float*)d_in[8];
    const float* Wbr  = (const float*)d_in[9];
    const float* bbr  = (const float*)d_in[10];
    const float* Wt1  = (const float*)d_in[11];
    const float* bt1  = (const float*)d_in[12];
    const float* Wt2  = (const float*)d_in[13];
    const float* bt2  = (const float*)d_in[14];
    const float* Wo1  = (const float*)d_in[15];
    const float* bo1  = (const float*)d_in[16];
    const float* Wo2  = (const float*)d_in[17];
    const float* bo2  = (const float*)d_in[18];
    float* ws  = (float*)d_ws;
    float* out = (float*)d_out;

    hipLaunchKernelGGL(norms_k, dim3(5), dim3(256), 0, stream, Wih, Whh, Wbr, Wo1, Wo2, ws);
    hipLaunchKernelGGL(prep_k, dim3(256), dim3(256), 0, stream,
                       Wih, Whh, bih, bhh, Wbr, Wt1, Wo1, Wo2, ws);
    hipLaunchKernelGGL(crn_main, dim3(BATCH / 16), dim3(256), 0, stream,
                       cov, trt, h0, c0, bbr, bt1, Wt2, bt2, bo1, bo2, ws, out);
}